// Round 7
// baseline (790.025 us; speedup 1.0000x reference)
//
#include <hip/hip_runtime.h>
#include <hip/hip_cooperative_groups.h>

namespace cg = cooperative_groups;

#define N_NODES 50000
#define N_EDGES 800000
#define M_IDX   25000
#define NT      ((N_NODES + 255) / 256)   // 196 scan tiles
#define CHUNK   196                       // nodes per thread in 1-block scan

struct Params {
    const float* x;   const float* pos;
    const float* lw0; const float* lb0; const float* gm0; const float* bt0;
    const float* rt0; const float* bs0;
    const float* lw1; const float* lb1; const float* gm1; const float* bt1;
    const float* rt1; const float* bs1;
    const float* lw2; const float* lb2; const float* gm2; const float* bt2;
    const float* rt2; const float* bs2;
    const int* batch; const int* idx; const int* ei;
    float4* pp; float* mbuf; float* hA; float* hB;
    int* cnt; int* off; int* cursor; int* tsum;
    float* out;
};

template<int CI>
__device__ __forceinline__ void load_row(const float* __restrict__ h, int s, float (&xr)[CI]) {
    const float4* xp = (const float4*)(h + (size_t)s * CI);
#pragma unroll
    for (int q = 0; q < CI / 4; ++q) {
        float4 a = xp[q];
        xr[4*q+0] = a.x; xr[4*q+1] = a.y; xr[4*q+2] = a.z; xr[4*q+3] = a.w;
    }
}

// Edge phase: 16 lanes/slot, folded weights in regs; depth-2 pipeline:
// pd prefetched 2 iters ahead, x rows 1 iter ahead (waits sink past compute).
template<int CI>
__device__ __forceinline__ void edge_phase(
    const float4* __restrict__ pp, const float* __restrict__ h_in,
    const float* __restrict__ lin_w, const float* __restrict__ lin_b,
    const float* __restrict__ gamma, const float* __restrict__ beta,
    float* __restrict__ mbuf, int tid, int nth)
{
    const int o = tid & 15;
    const int d = CI * 16;
    float W0[CI], W1[CI], W2[CI], B[CI];
#pragma unroll
    for (int i = 0; i < CI; ++i) {
        int j = i * 16 + o;
        float gmv = gamma[j];
        W0[i] = lin_w[j] * gmv;
        W1[i] = lin_w[d + j] * gmv;
        W2[i] = lin_w[2 * d + j] * gmv;
        B[i]  = fmaf(lin_b[j], gmv, beta[j]);
    }
    const int g    = tid >> 4;
    const int ng   = nth >> 4;
    const int step = 2 * ng;
    const int E    = N_EDGES;

    int s0 = g;
    float4 pdA  = pp[min(s0, E - 1)];
    float4 pdB  = pp[min(s0 + ng, E - 1)];
    float4 pdA2 = pp[min(s0 + step, E - 1)];
    float4 pdB2 = pp[min(s0 + ng + step, E - 1)];
    float xA[CI], xB[CI], xA2[CI], xB2[CI];
    load_row<CI>(h_in, __float_as_int(pdA.w), xA);
    load_row<CI>(h_in, __float_as_int(pdB.w), xB);

    while (s0 < E) {
        float4 pdA3 = pp[min(s0 + 2 * step, E - 1)];
        float4 pdB3 = pp[min(s0 + ng + 2 * step, E - 1)];
        load_row<CI>(h_in, __float_as_int(pdA2.w), xA2);
        load_row<CI>(h_in, __float_as_int(pdB2.w), xB2);
        float aA = 0.f, aB = 0.f;
#pragma unroll
        for (int i = 0; i < CI; ++i) {
            float wA = fmaf(pdA.x, W0[i], fmaf(pdA.y, W1[i], fmaf(pdA.z, W2[i], B[i])));
            aA = fmaf(xA[i], fmaxf(wA, 0.f), aA);
            float wB = fmaf(pdB.x, W0[i], fmaf(pdB.y, W1[i], fmaf(pdB.z, W2[i], B[i])));
            aB = fmaf(xB[i], fmaxf(wB, 0.f), aB);
        }
        mbuf[(size_t)s0 * 16 + o] = aA;
        int s1 = s0 + ng;
        if (s1 < E) mbuf[(size_t)s1 * 16 + o] = aB;
        pdA = pdA2; pdB = pdB2; pdA2 = pdA3; pdB2 = pdB3;
#pragma unroll
        for (int i = 0; i < CI; ++i) { xA[i] = xA2[i]; xB[i] = xB2[i]; }
        s0 += step;
    }
}

// Node phase (intermediate layers): thread per (node,channel); mbuf is
// slot-ordered == node-ordered -> contiguous affine reads; fused epilogue.
template<int CI>
__device__ __forceinline__ void node_phase(
    const int* __restrict__ off, const int* __restrict__ cnt,
    const float* __restrict__ mbuf, const float* __restrict__ h_in,
    const float* __restrict__ root, const float* __restrict__ bias,
    float* __restrict__ h_out, int tid, int nth)
{
    for (int t16 = tid; t16 < N_NODES * 16; t16 += nth) {
        const int t = t16 >> 4, o = t16 & 15;
        const int deg = cnt[t];
        const float* mp = mbuf + (size_t)off[t] * 16 + o;
        float acc = 0.f;
        int p = 0;
        for (; p + 4 <= deg; p += 4) {
            float a0 = mp[(p+0)*16], a1 = mp[(p+1)*16];
            float a2 = mp[(p+2)*16], a3 = mp[(p+3)*16];
            acc += (a0 + a1) + (a2 + a3);
        }
        for (; p < deg; ++p) acc += mp[p * 16];
        float r = fmaf(acc, 1.0f / fmaxf((float)deg, 1.0f), bias[o]);
        const float4* hp = (const float4*)(h_in + (size_t)t * CI);
#pragma unroll
        for (int q = 0; q < CI / 4; ++q) {
            float4 v = hp[q];
            r = fmaf(v.x, root[(4*q+0)*16 + o], r);
            r = fmaf(v.y, root[(4*q+1)*16 + o], r);
            r = fmaf(v.z, root[(4*q+2)*16 + o], r);
            r = fmaf(v.w, root[(4*q+3)*16 + o], r);
        }
        h_out[t16] = fmaxf(r, 0.f);
    }
}

// Final phase: compute ONLY the selected nodes (idx), write h|pos|batch out.
__device__ __forceinline__ void final_phase(
    const int* __restrict__ off, const int* __restrict__ cnt,
    const float* __restrict__ mbuf, const float* __restrict__ h_in,
    const float* __restrict__ root, const float* __restrict__ bias,
    const float* __restrict__ pos, const int* __restrict__ batch,
    const int* __restrict__ idx, float* __restrict__ out, int tid, int nth)
{
    const int CI = 16;
    for (int j16 = tid; j16 < M_IDX * 16; j16 += nth) {
        const int j = j16 >> 4, o = j16 & 15;
        const int n = idx[j];
        const int deg = cnt[n];
        const float* mp = mbuf + (size_t)off[n] * 16 + o;
        float acc = 0.f;
        int p = 0;
        for (; p + 4 <= deg; p += 4) {
            float a0 = mp[(p+0)*16], a1 = mp[(p+1)*16];
            float a2 = mp[(p+2)*16], a3 = mp[(p+3)*16];
            acc += (a0 + a1) + (a2 + a3);
        }
        for (; p < deg; ++p) acc += mp[p * 16];
        float r = fmaf(acc, 1.0f / fmaxf((float)deg, 1.0f), bias[o]);
        const float4* hp = (const float4*)(h_in + (size_t)n * CI);
#pragma unroll
        for (int q = 0; q < CI / 4; ++q) {
            float4 v = hp[q];
            r = fmaf(v.x, root[(4*q+0)*16 + o], r);
            r = fmaf(v.y, root[(4*q+1)*16 + o], r);
            r = fmaf(v.z, root[(4*q+2)*16 + o], r);
            r = fmaf(v.w, root[(4*q+3)*16 + o], r);
        }
        out[j * 16 + o] = fmaxf(r, 0.f);
        if (o < 3)  out[(size_t)M_IDX * 16 + j * 3 + o] = pos[n * 3 + o];
        if (o == 3) ((int*)out)[(size_t)M_IDX * 19 + j] = batch[n];
    }
}

// ===========================================================================
// Path 1: single cooperative kernel
// ===========================================================================
__global__ __launch_bounds__(256) void fused_all(Params P)
{
    cg::grid_group grid = cg::this_grid();
    const int tid = blockIdx.x * 256 + threadIdx.x;
    const int nth = gridDim.x * 256;
    __shared__ int sh[256];

    for (int i = tid; i < N_NODES; i += nth) P.cnt[i] = 0;
    grid.sync();
    for (int e = tid; e < N_EDGES; e += nth) atomicAdd(&P.cnt[P.ei[N_EDGES + e]], 1);
    grid.sync();
    for (int t = blockIdx.x; t < NT; t += gridDim.x) {
        int i = t * 256 + threadIdx.x;
        int v = (i < N_NODES) ? P.cnt[i] : 0;
        sh[threadIdx.x] = v; __syncthreads();
        for (int dd = 1; dd < 256; dd <<= 1) {
            int tv = (threadIdx.x >= dd) ? sh[threadIdx.x - dd] : 0;
            __syncthreads(); sh[threadIdx.x] += tv; __syncthreads();
        }
        if (i < N_NODES) P.off[i] = sh[threadIdx.x] - v;
        if (threadIdx.x == 255) P.tsum[t] = sh[255];
        __syncthreads();
    }
    grid.sync();
    if (blockIdx.x == 0) {
        int v = (threadIdx.x < NT) ? P.tsum[threadIdx.x] : 0;
        sh[threadIdx.x] = v; __syncthreads();
        for (int dd = 1; dd < 256; dd <<= 1) {
            int tv = (threadIdx.x >= dd) ? sh[threadIdx.x - dd] : 0;
            __syncthreads(); sh[threadIdx.x] += tv; __syncthreads();
        }
        if (threadIdx.x < NT) P.tsum[threadIdx.x] = sh[threadIdx.x] - v;
    }
    grid.sync();
    for (int i = tid; i < N_NODES; i += nth) {
        int o2 = P.off[i] + P.tsum[i >> 8];
        P.off[i] = o2; P.cursor[i] = o2;
    }
    grid.sync();
    for (int e = tid; e < N_EDGES; e += nth) {
        int s = P.ei[e], t = P.ei[N_EDGES + e];
        float4 pd;
        pd.x = P.pos[t*3+0] - P.pos[s*3+0];
        pd.y = P.pos[t*3+1] - P.pos[s*3+1];
        pd.z = P.pos[t*3+2] - P.pos[s*3+2];
        pd.w = __int_as_float(s);
        int slot = atomicAdd(&P.cursor[t], 1);
        P.pp[slot] = pd;
    }
    grid.sync();

    edge_phase<8>(P.pp, P.x, P.lw0, P.lb0, P.gm0, P.bt0, P.mbuf, tid, nth);
    grid.sync();
    node_phase<8>(P.off, P.cnt, P.mbuf, P.x, P.rt0, P.bs0, P.hA, tid, nth);
    grid.sync();
    edge_phase<16>(P.pp, P.hA, P.lw1, P.lb1, P.gm1, P.bt1, P.mbuf, tid, nth);
    grid.sync();
    node_phase<16>(P.off, P.cnt, P.mbuf, P.hA, P.rt1, P.bs1, P.hB, tid, nth);
    grid.sync();
    edge_phase<16>(P.pp, P.hB, P.lw2, P.lb2, P.gm2, P.bt2, P.mbuf, tid, nth);
    grid.sync();
    final_phase(P.off, P.cnt, P.mbuf, P.hB, P.rt2, P.bs2, P.pos, P.batch, P.idx,
                P.out, tid, nth);
}

// ===========================================================================
// Path 2: multi-dispatch fallback (9 dispatches)
// ===========================================================================
__global__ __launch_bounds__(256) void hist_kernel(const int* __restrict__ dst,
                                                   int* __restrict__ cnt) {
    int e = blockIdx.x * 256 + threadIdx.x;
    if (e < N_EDGES) atomicAdd(&cnt[dst[e]], 1);
}

// zero + exclusive scan in ONE single-block dispatch (cnt pre-computed)
__global__ __launch_bounds__(256) void scan_all_kernel(
    const int* __restrict__ cnt, int* __restrict__ off, int* __restrict__ cursor)
{
    __shared__ int sh[256];
    const int t = threadIdx.x;
    const int lo = t * CHUNK;
    const int hi = min(lo + CHUNK, N_NODES);
    int s = 0;
    for (int i = lo; i < hi; ++i) s += cnt[i];
    sh[t] = s; __syncthreads();
    for (int d = 1; d < 256; d <<= 1) {
        int v = (t >= d) ? sh[t - d] : 0;
        __syncthreads(); sh[t] += v; __syncthreads();
    }
    int run = sh[t] - s;
    for (int i = lo; i < hi; ++i) {
        off[i] = run; cursor[i] = run; run += cnt[i];
    }
}

__global__ __launch_bounds__(256) void fill_kernel(
    const int* __restrict__ ei, const float* __restrict__ pos,
    int* __restrict__ cursor, float4* __restrict__ pp)
{
    int e = blockIdx.x * 256 + threadIdx.x;
    if (e >= N_EDGES) return;
    int s = ei[e], t = ei[N_EDGES + e];
    float4 pd;
    pd.x = pos[t*3+0] - pos[s*3+0];
    pd.y = pos[t*3+1] - pos[s*3+1];
    pd.z = pos[t*3+2] - pos[s*3+2];
    pd.w = __int_as_float(s);
    int slot = atomicAdd(&cursor[t], 1);
    pp[slot] = pd;
}

template<int CI>
__global__ __launch_bounds__(256) void edge_msg_kernel(
    const float4* __restrict__ pp, const float* __restrict__ h_in,
    const float* __restrict__ lin_w, const float* __restrict__ lin_b,
    const float* __restrict__ gamma, const float* __restrict__ beta,
    float* __restrict__ mbuf)
{
    edge_phase<CI>(pp, h_in, lin_w, lin_b, gamma, beta, mbuf,
                   blockIdx.x * 256 + threadIdx.x, gridDim.x * 256);
}

template<int CI>
__global__ __launch_bounds__(256) void node_out_kernel(
    const int* __restrict__ off, const int* __restrict__ cnt,
    const float* __restrict__ mbuf, const float* __restrict__ h_in,
    const float* __restrict__ root, const float* __restrict__ bias,
    float* __restrict__ h_out)
{
    node_phase<CI>(off, cnt, mbuf, h_in, root, bias, h_out,
                   blockIdx.x * 256 + threadIdx.x, gridDim.x * 256);
}

__global__ __launch_bounds__(256) void final_kernel(
    const int* __restrict__ off, const int* __restrict__ cnt,
    const float* __restrict__ mbuf, const float* __restrict__ h_in,
    const float* __restrict__ root, const float* __restrict__ bias,
    const float* __restrict__ pos, const int* __restrict__ batch,
    const int* __restrict__ idx, float* __restrict__ out)
{
    final_phase(off, cnt, mbuf, h_in, root, bias, pos, batch, idx, out,
                blockIdx.x * 256 + threadIdx.x, gridDim.x * 256);
}

extern "C" void kernel_launch(void* const* d_in, const int* in_sizes, int n_in,
                              void* d_out, int out_size, void* d_ws, size_t ws_size,
                              hipStream_t stream) {
    Params P;
    P.x   = (const float*)d_in[0];
    P.pos = (const float*)d_in[1];
    P.lw0 = (const float*)d_in[2];  P.lb0 = (const float*)d_in[3];
    P.gm0 = (const float*)d_in[4];  P.bt0 = (const float*)d_in[5];
    P.rt0 = (const float*)d_in[6];  P.bs0 = (const float*)d_in[7];
    P.lw1 = (const float*)d_in[8];  P.lb1 = (const float*)d_in[9];
    P.gm1 = (const float*)d_in[10]; P.bt1 = (const float*)d_in[11];
    P.rt1 = (const float*)d_in[12]; P.bs1 = (const float*)d_in[13];
    P.lw2 = (const float*)d_in[14]; P.lb2 = (const float*)d_in[15];
    P.gm2 = (const float*)d_in[16]; P.bt2 = (const float*)d_in[17];
    P.rt2 = (const float*)d_in[18]; P.bs2 = (const float*)d_in[19];
    P.batch = (const int*)d_in[20];
    P.idx   = (const int*)d_in[21];
    P.ei    = (const int*)d_in[22];

    P.pp     = (float4*)d_ws;                                // E float4 (12.8 MB)
    P.mbuf   = (float*)(P.pp + N_EDGES);                     // E*16 floats (51.2 MB)
    P.hA     = P.mbuf + (size_t)N_EDGES * 16;                // N*16 floats
    P.hB     = P.hA + (size_t)N_NODES * 16;                  // N*16 floats
    P.cnt    = (int*)(P.hB + (size_t)N_NODES * 16);          // N ints
    P.off    = P.cnt + N_NODES;                              // N ints
    P.cursor = P.off + N_NODES;                              // N ints
    P.tsum   = P.cursor + N_NODES;                           // 256 ints
    P.out    = (float*)d_out;

    // ---- try single cooperative kernel, sized by queried occupancy ----
    bool coop_ok = false;
    int nb = 0;
    if (hipOccupancyMaxActiveBlocksPerMultiprocessor(
            &nb, reinterpret_cast<const void*>(fused_all), 256, 0) == hipSuccess
        && nb >= 1) {
        int grid = nb * 256;            // 256 CUs on MI355X
        if (grid > 1024) grid = 1024;
        void* args[] = { &P };
        hipError_t err = hipLaunchCooperativeKernel(
            reinterpret_cast<void*>(fused_all), dim3(grid), dim3(256), args, 0, stream);
        coop_ok = (err == hipSuccess);
        if (!coop_ok) (void)hipGetLastError();   // clear error state
    } else {
        (void)hipGetLastError();
    }
    if (coop_ok) return;

    // ---- fallback: 9-dispatch pipeline ----
    const int EBLK = (N_EDGES + 255) / 256;          // 3125
    const int EB   = 2048;                           // edge grid (grid-stride)
    const int NB   = (N_NODES * 16 + 255) / 256;     // 3125
    const int FB   = (M_IDX * 16 + 255) / 256;       // 1563

    hipMemsetAsync(P.cnt, 0, N_NODES * sizeof(int), stream);
    hist_kernel<<<EBLK, 256, 0, stream>>>(P.ei + N_EDGES, P.cnt);
    scan_all_kernel<<<1, 256, 0, stream>>>(P.cnt, P.off, P.cursor);
    fill_kernel<<<EBLK, 256, 0, stream>>>(P.ei, P.pos, P.cursor, P.pp);

    edge_msg_kernel<8><<<EB, 256, 0, stream>>>(P.pp, P.x, P.lw0, P.lb0, P.gm0, P.bt0, P.mbuf);
    node_out_kernel<8><<<NB, 256, 0, stream>>>(P.off, P.cnt, P.mbuf, P.x, P.rt0, P.bs0, P.hA);
    edge_msg_kernel<16><<<EB, 256, 0, stream>>>(P.pp, P.hA, P.lw1, P.lb1, P.gm1, P.bt1, P.mbuf);
    node_out_kernel<16><<<NB, 256, 0, stream>>>(P.off, P.cnt, P.mbuf, P.hA, P.rt1, P.bs1, P.hB);
    edge_msg_kernel<16><<<EB, 256, 0, stream>>>(P.pp, P.hB, P.lw2, P.lb2, P.gm2, P.bt2, P.mbuf);
    final_kernel<<<FB, 256, 0, stream>>>(P.off, P.cnt, P.mbuf, P.hB, P.rt2, P.bs2,
                                         P.pos, P.batch, P.idx, P.out);
}

// Round 8
// 484.370 us; speedup vs baseline: 1.6310x; 1.6310x over previous
//
#include <hip/hip_runtime.h>

#define N_NODES 50000
#define N_EDGES 800000
#define M_IDX   25000
#define CHUNK   196   // nodes per thread in the single-block scan (256*196 >= N)

// ---------------------------------------------------------------------------
// Prep 1: degree histogram (cnt pre-zeroed by hipMemsetAsync)
// ---------------------------------------------------------------------------
__global__ __launch_bounds__(256) void hist_kernel(
    const int* __restrict__ dst, int* __restrict__ cnt)
{
    int e = blockIdx.x * 256 + threadIdx.x;
    if (e < N_EDGES) atomicAdd(&cnt[dst[e]], 1);
}

// ---------------------------------------------------------------------------
// Prep 2: exclusive scan in ONE single-block dispatch
// ---------------------------------------------------------------------------
__global__ __launch_bounds__(256) void scan_all_kernel(
    const int* __restrict__ cnt, int* __restrict__ off, int* __restrict__ cursor)
{
    __shared__ int sh[256];
    const int t = threadIdx.x;
    const int lo = t * CHUNK;
    const int hi = min(lo + CHUNK, N_NODES);
    int s = 0;
    for (int i = lo; i < hi; ++i) s += cnt[i];
    sh[t] = s; __syncthreads();
    for (int d = 1; d < 256; d <<= 1) {
        int v = (t >= d) ? sh[t - d] : 0;
        __syncthreads(); sh[t] += v; __syncthreads();
    }
    int run = sh[t] - s;
    for (int i = lo; i < hi; ++i) {
        off[i] = run; cursor[i] = run; run += cnt[i];
    }
}

// ---------------------------------------------------------------------------
// Prep 3a: scatter only 4B edge ids into slot order (low write thrash)
// ---------------------------------------------------------------------------
__global__ __launch_bounds__(256) void fill_eid_kernel(
    const int* __restrict__ dst, int* __restrict__ cursor, int* __restrict__ eids)
{
    int e = blockIdx.x * 256 + threadIdx.x;
    if (e >= N_EDGES) return;
    int slot = atomicAdd(&cursor[dst[e]], 1);
    eids[slot] = e;
}

// ---------------------------------------------------------------------------
// Prep 3b: build payload coalesced: pp[slot] = {pseudo.xyz, src-bits}
// (eids read coalesced; ei/pos gathers are L2-resident; pp write coalesced)
// ---------------------------------------------------------------------------
__global__ __launch_bounds__(256) void fill_pp_kernel(
    const int* __restrict__ eids, const int* __restrict__ ei,
    const float* __restrict__ pos, float4* __restrict__ pp)
{
    int slot = blockIdx.x * 256 + threadIdx.x;
    if (slot >= N_EDGES) return;
    int e = eids[slot];
    int s = ei[e], t = ei[N_EDGES + e];
    float4 pd;
    pd.x = pos[t*3+0] - pos[s*3+0];
    pd.y = pos[t*3+1] - pos[s*3+1];
    pd.z = pos[t*3+2] - pos[s*3+2];
    pd.w = __int_as_float(s);
    pp[slot] = pd;
}

// ---------------------------------------------------------------------------
// Edge phase: 16 lanes/slot, folded weights in regs; depth-2 pipeline:
// pd prefetched 2 iters ahead, x rows 1 iter ahead.
// ---------------------------------------------------------------------------
template<int CI>
__device__ __forceinline__ void load_row(const float* __restrict__ h, int s, float (&xr)[CI]) {
    const float4* xp = (const float4*)(h + (size_t)s * CI);
#pragma unroll
    for (int q = 0; q < CI / 4; ++q) {
        float4 a = xp[q];
        xr[4*q+0] = a.x; xr[4*q+1] = a.y; xr[4*q+2] = a.z; xr[4*q+3] = a.w;
    }
}

template<int CI>
__global__ __launch_bounds__(256) void edge_msg_kernel(
    const float4* __restrict__ pp, const float* __restrict__ h_in,
    const float* __restrict__ lin_w, const float* __restrict__ lin_b,
    const float* __restrict__ gamma, const float* __restrict__ beta,
    float* __restrict__ mbuf)
{
    const int tid = blockIdx.x * 256 + threadIdx.x;
    const int nth = gridDim.x * 256;
    const int o = tid & 15;
    const int d = CI * 16;
    float W0[CI], W1[CI], W2[CI], B[CI];
#pragma unroll
    for (int i = 0; i < CI; ++i) {
        int j = i * 16 + o;
        float gmv = gamma[j];
        W0[i] = lin_w[j] * gmv;
        W1[i] = lin_w[d + j] * gmv;
        W2[i] = lin_w[2 * d + j] * gmv;
        B[i]  = fmaf(lin_b[j], gmv, beta[j]);
    }
    const int g    = tid >> 4;
    const int ng   = nth >> 4;
    const int step = 2 * ng;
    const int E    = N_EDGES;

    int s0 = g;
    float4 pdA  = pp[min(s0, E - 1)];
    float4 pdB  = pp[min(s0 + ng, E - 1)];
    float4 pdA2 = pp[min(s0 + step, E - 1)];
    float4 pdB2 = pp[min(s0 + ng + step, E - 1)];
    float xA[CI], xB[CI], xA2[CI], xB2[CI];
    load_row<CI>(h_in, __float_as_int(pdA.w), xA);
    load_row<CI>(h_in, __float_as_int(pdB.w), xB);

    while (s0 < E) {
        float4 pdA3 = pp[min(s0 + 2 * step, E - 1)];
        float4 pdB3 = pp[min(s0 + ng + 2 * step, E - 1)];
        load_row<CI>(h_in, __float_as_int(pdA2.w), xA2);
        load_row<CI>(h_in, __float_as_int(pdB2.w), xB2);
        float aA = 0.f, aB = 0.f;
#pragma unroll
        for (int i = 0; i < CI; ++i) {
            float wA = fmaf(pdA.x, W0[i], fmaf(pdA.y, W1[i], fmaf(pdA.z, W2[i], B[i])));
            aA = fmaf(xA[i], fmaxf(wA, 0.f), aA);
            float wB = fmaf(pdB.x, W0[i], fmaf(pdB.y, W1[i], fmaf(pdB.z, W2[i], B[i])));
            aB = fmaf(xB[i], fmaxf(wB, 0.f), aB);
        }
        mbuf[(size_t)s0 * 16 + o] = aA;
        int s1 = s0 + ng;
        if (s1 < E) mbuf[(size_t)s1 * 16 + o] = aB;
        pdA = pdA2; pdB = pdB2; pdA2 = pdA3; pdB2 = pdB3;
#pragma unroll
        for (int i = 0; i < CI; ++i) { xA[i] = xA2[i]; xB[i] = xB2[i]; }
        s0 += step;
    }
}

// ---------------------------------------------------------------------------
// Node phase (layers 0,1): thread per (node,channel); mbuf is slot-ordered
// == node-ordered -> contiguous affine reads; fused mean+rootGEMV+bias+ReLU.
// ---------------------------------------------------------------------------
template<int CI>
__global__ __launch_bounds__(256) void node_out_kernel(
    const int* __restrict__ off, const int* __restrict__ cnt,
    const float* __restrict__ mbuf, const float* __restrict__ h_in,
    const float* __restrict__ root, const float* __restrict__ bias,
    float* __restrict__ h_out)
{
    int t16 = blockIdx.x * 256 + threadIdx.x;
    if (t16 >= N_NODES * 16) return;
    const int t = t16 >> 4, o = t16 & 15;
    const int deg = cnt[t];
    const float* mp = mbuf + (size_t)off[t] * 16 + o;
    float acc = 0.f;
    int p = 0;
    for (; p + 4 <= deg; p += 4) {
        float a0 = mp[(p+0)*16], a1 = mp[(p+1)*16];
        float a2 = mp[(p+2)*16], a3 = mp[(p+3)*16];
        acc += (a0 + a1) + (a2 + a3);
    }
    for (; p < deg; ++p) acc += mp[p * 16];
    float r = fmaf(acc, 1.0f / fmaxf((float)deg, 1.0f), bias[o]);
    const float4* hp = (const float4*)(h_in + (size_t)t * CI);
#pragma unroll
    for (int q = 0; q < CI / 4; ++q) {
        float4 v = hp[q];
        r = fmaf(v.x, root[(4*q+0)*16 + o], r);
        r = fmaf(v.y, root[(4*q+1)*16 + o], r);
        r = fmaf(v.z, root[(4*q+2)*16 + o], r);
        r = fmaf(v.w, root[(4*q+3)*16 + o], r);
    }
    h_out[t16] = fmaxf(r, 0.f);
}

// ---------------------------------------------------------------------------
// Final: layer-2 node epilogue computed ONLY at the 25k selected nodes,
// fused with the output gather (h|pos|batch).
// ---------------------------------------------------------------------------
__global__ __launch_bounds__(256) void final_kernel(
    const int* __restrict__ off, const int* __restrict__ cnt,
    const float* __restrict__ mbuf, const float* __restrict__ h_in,
    const float* __restrict__ root, const float* __restrict__ bias,
    const float* __restrict__ pos, const int* __restrict__ batch,
    const int* __restrict__ idx, float* __restrict__ out)
{
    const int CI = 16;
    int j16 = blockIdx.x * 256 + threadIdx.x;
    if (j16 >= M_IDX * 16) return;
    const int j = j16 >> 4, o = j16 & 15;
    const int n = idx[j];
    const int deg = cnt[n];
    const float* mp = mbuf + (size_t)off[n] * 16 + o;
    float acc = 0.f;
    int p = 0;
    for (; p + 4 <= deg; p += 4) {
        float a0 = mp[(p+0)*16], a1 = mp[(p+1)*16];
        float a2 = mp[(p+2)*16], a3 = mp[(p+3)*16];
        acc += (a0 + a1) + (a2 + a3);
    }
    for (; p < deg; ++p) acc += mp[p * 16];
    float r = fmaf(acc, 1.0f / fmaxf((float)deg, 1.0f), bias[o]);
    const float4* hp = (const float4*)(h_in + (size_t)n * CI);
#pragma unroll
    for (int q = 0; q < CI / 4; ++q) {
        float4 v = hp[q];
        r = fmaf(v.x, root[(4*q+0)*16 + o], r);
        r = fmaf(v.y, root[(4*q+1)*16 + o], r);
        r = fmaf(v.z, root[(4*q+2)*16 + o], r);
        r = fmaf(v.w, root[(4*q+3)*16 + o], r);
    }
    out[j * 16 + o] = fmaxf(r, 0.f);
    if (o < 3)  out[(size_t)M_IDX * 16 + j * 3 + o] = pos[n * 3 + o];
    if (o == 3) ((int*)out)[(size_t)M_IDX * 19 + j] = batch[n];
}

extern "C" void kernel_launch(void* const* d_in, const int* in_sizes, int n_in,
                              void* d_out, int out_size, void* d_ws, size_t ws_size,
                              hipStream_t stream) {
    const float* x   = (const float*)d_in[0];
    const float* pos = (const float*)d_in[1];
    const float* lw0 = (const float*)d_in[2];  const float* lb0 = (const float*)d_in[3];
    const float* gm0 = (const float*)d_in[4];  const float* bt0 = (const float*)d_in[5];
    const float* rt0 = (const float*)d_in[6];  const float* bs0 = (const float*)d_in[7];
    const float* lw1 = (const float*)d_in[8];  const float* lb1 = (const float*)d_in[9];
    const float* gm1 = (const float*)d_in[10]; const float* bt1 = (const float*)d_in[11];
    const float* rt1 = (const float*)d_in[12]; const float* bs1 = (const float*)d_in[13];
    const float* lw2 = (const float*)d_in[14]; const float* lb2 = (const float*)d_in[15];
    const float* gm2 = (const float*)d_in[16]; const float* bt2 = (const float*)d_in[17];
    const float* rt2 = (const float*)d_in[18]; const float* bs2 = (const float*)d_in[19];
    const int*   batch = (const int*)d_in[20];
    const int*   idx   = (const int*)d_in[21];
    const int*   ei    = (const int*)d_in[22];
    const int*   dst   = ei + N_EDGES;
    float*       out   = (float*)d_out;

    // workspace layout (16B aligned)
    float4* pp     = (float4*)d_ws;                          // E float4 (12.8 MB)
    float*  mbuf   = (float*)(pp + N_EDGES);                 // E*16 floats (51.2 MB)
    float*  hA     = mbuf + (size_t)N_EDGES * 16;            // N*16 floats
    float*  hB     = hA + (size_t)N_NODES * 16;              // N*16 floats
    int*    eids   = (int*)(hB + (size_t)N_NODES * 16);      // E ints (3.2 MB)
    int*    cnt    = eids + N_EDGES;                         // N ints
    int*    off    = cnt + N_NODES;                          // N ints
    int*    cursor = off + N_NODES;                          // N ints

    const int EBLK = (N_EDGES + 255) / 256;          // 3125
    const int EB   = 2048;                           // edge grid (grid-stride)
    const int NB   = (N_NODES * 16 + 255) / 256;     // 3125
    const int FB   = (M_IDX * 16 + 255) / 256;       // 1563

    // ---- prep ----
    hipMemsetAsync(cnt, 0, N_NODES * sizeof(int), stream);
    hist_kernel<<<EBLK, 256, 0, stream>>>(dst, cnt);
    scan_all_kernel<<<1, 256, 0, stream>>>(cnt, off, cursor);
    fill_eid_kernel<<<EBLK, 256, 0, stream>>>(dst, cursor, eids);
    fill_pp_kernel<<<EBLK, 256, 0, stream>>>(eids, ei, pos, pp);

    // ---- 3 layers ----
    edge_msg_kernel<8><<<EB, 256, 0, stream>>>(pp, x, lw0, lb0, gm0, bt0, mbuf);
    node_out_kernel<8><<<NB, 256, 0, stream>>>(off, cnt, mbuf, x, rt0, bs0, hA);
    edge_msg_kernel<16><<<EB, 256, 0, stream>>>(pp, hA, lw1, lb1, gm1, bt1, mbuf);
    node_out_kernel<16><<<NB, 256, 0, stream>>>(off, cnt, mbuf, hA, rt1, bs1, hB);
    edge_msg_kernel<16><<<EB, 256, 0, stream>>>(pp, hB, lw2, lb2, gm2, bt2, mbuf);
    final_kernel<<<FB, 256, 0, stream>>>(off, cnt, mbuf, hB, rt2, bs2, pos, batch, idx, out);
}